// Round 10
// baseline (135.389 us; speedup 1.0000x reference)
//
#include <hip/hip_runtime.h>

typedef unsigned short u16;
typedef unsigned int u32;
typedef short v8s __attribute__((ext_vector_type(8)));
typedef float v4f __attribute__((ext_vector_type(4)));
typedef float v2f __attribute__((ext_vector_type(2)));

__device__ __forceinline__ float bflo(u32 d){union{u32 i;float f;}u;u.i=d<<16;return u.f;}
__device__ __forceinline__ float bfhi(u32 d){union{u32 i;float f;}u;u.i=d&0xffff0000u;return u.f;}
__device__ __forceinline__ u16 f2bfr(float f){union{float f;u32 i;}u;u.f=f;return (u16)((u.i+0x8000u)>>16);}
__device__ __forceinline__ u32 pk2bf(float a,float b){
    union{float f;u32 i;}ua,ub; ua.f=a; ub.f=b;
    u32 x = ua.i + 0x8000u, y = ub.i + 0x8000u;
    return __builtin_amdgcn_perm(y, x, 0x07060302);
}
__device__ __forceinline__ v8s pack8(const float* w){
    union { uint4 u; v8s v; } c;
    c.u.x = pk2bf(w[0],w[1]); c.u.y = pk2bf(w[2],w[3]);
    c.u.z = pk2bf(w[4],w[5]); c.u.w = pk2bf(w[6],w[7]);
    return c.v;
}

// Flash S@Wh, two 16-row strips per wave; adj from global (L2-hot).
// w = adj * max(Ei*Ej, Fi*Fj) == adj * exp(lrelu(ei+ej))
__device__ __forceinline__ void flash_att(
    int wv, int l15, int q4,
    const float* __restrict__ ADJ,
    const float* __restrict__ sEi, const float* __restrict__ sFi,
    const float* __restrict__ sEj, const float* __restrict__ sFj,
    const u16* __restrict__ sWhT,
    v4f acc[2][4], float invD[2])
{
    const int r0 = 16*wv + l15, r1 = r0 + 64;
    const v2f Ei0 = {sEi[r0], sEi[r0]}, Fi0 = {sFi[r0], sFi[r0]};
    const v2f Ei1 = {sEi[r1], sEi[r1]}, Fi1 = {sFi[r1], sFi[r1]};
    v2f D0 = {0.f,0.f}, D1 = {0.f,0.f};
    #pragma unroll
    for (int s = 0; s < 2; ++s)
        #pragma unroll
        for (int ct = 0; ct < 4; ++ct) acc[s][ct] = (v4f){0.f,0.f,0.f,0.f};

    #pragma unroll
    for (int ks = 0; ks < 4; ++ks) {
        const int ko = ks*32 + q4*8;
        const v2f* Ejp = (const v2f*)(sEj + ko);
        const v2f* Fjp = (const v2f*)(sFj + ko);
        const v2f* A0p = (const v2f*)(ADJ + r0*128 + ko);
        const v2f* A1p = (const v2f*)(ADJ + r1*128 + ko);
        union { u32 u[4]; v8s v; } P0, P1;
        #pragma unroll
        for (int p = 0; p < 4; ++p) {
            v2f E = Ejp[p], F = Fjp[p];
            v2f a0 = A0p[p], a1 = A1p[p];
            v2f m0 = __builtin_elementwise_max(Ei0*E, Fi0*F);
            v2f m1 = __builtin_elementwise_max(Ei1*E, Fi1*F);
            v2f x0 = m0 * a0;
            v2f x1 = m1 * a1;
            D0 += x0; D1 += x1;
            P0.u[p] = pk2bf(x0.x, x0.y);
            P1.u[p] = pk2bf(x1.x, x1.y);
        }
        #pragma unroll
        for (int ct = 0; ct < 4; ++ct) {
            v8s B = *(const v8s*)(sWhT + (16*ct + l15)*136 + ko);
            acc[0][ct] = __builtin_amdgcn_mfma_f32_16x16x32_bf16(P0.v, B, acc[0][ct], 0,0,0);
            acc[1][ct] = __builtin_amdgcn_mfma_f32_16x16x32_bf16(P1.v, B, acc[1][ct], 0,0,0);
        }
    }
    float d0 = D0.x + D0.y, d1 = D1.x + D1.y;
    d0 += __shfl_xor(d0, 16); d0 += __shfl_xor(d0, 32);
    d1 += __shfl_xor(d1, 16); d1 += __shfl_xor(d1, 32);
    invD[0] = 1.f / d0; invD[1] = 1.f / d1;
}

// LDS budget ~26.3 KB -> 6 blocks/CU (24 waves). launch_bounds(256,5) caps VGPR at 102 (no spill).
__global__ __launch_bounds__(256, 5) void graphmixer_kernel(
    const float* __restrict__ C,     // (1024,128)
    const float* __restrict__ ADJ,   // (128,128)
    const float* __restrict__ EMB,   // (128,8)
    const float* __restrict__ W1,    // (9,64)
    const float* __restrict__ A1,    // (128)
    const float* __restrict__ W2,    // (64,64)
    const float* __restrict__ A2,    // (128)
    const float* __restrict__ LN1G, const float* __restrict__ LN1B,
    const float* __restrict__ LN2G, const float* __restrict__ LN2B,
    const float* __restrict__ HGW,  const float* __restrict__ HGB,
    const float* __restrict__ MLP1W, const float* __restrict__ MLP1B,
    const float* __restrict__ MLP2W, const float* __restrict__ MLP2B,
    const float* __restrict__ HMW,  const float* __restrict__ HMB,
    const float* __restrict__ G1W,  const float* __restrict__ G1B,
    const float* __restrict__ G2W,  const float* __restrict__ G2B,
    float* __restrict__ OUT)
{
    const int b = blockIdx.x, t = threadIdx.x;
    const int lane = t & 63, wv = t >> 6;
    const int l15 = lane & 15, q4 = lane >> 4;

    __shared__ __align__(16) unsigned char smem[26272];
    u16*   R1   = (u16*)(smem);            // 18432 B: Wh1T[64][136] -> H1[128][72] -> Wh2T[64][136]
    float* sEi  = (float*)(smem + 18432);  // 128
    float* sFi  = (float*)(smem + 18944);  // 128
    float* sEj  = (float*)(smem + 19456);  // 128
    float* sFj  = (float*)(smem + 19968);  // 128
    float* sScr = (float*)(smem + 20480);  // 136
    float* v2i  = (float*)(smem + 21024);  // 64
    float* v2j  = (float*)(smem + 21280);  // 64
    float* v1i  = (float*)(smem + 21536);  // 16
    float* v1j  = (float*)(smem + 21600);  // 16
    float* sEmb = (float*)(smem + 21664);  // 1024 (live P0..b2)
    float* sC   = (float*)(smem + 25760);  // 128  (live P0..b2)
    float* colp = (float*)(smem + 21664);  // 256  (aliases sEmb; live after b6)

    const float* Cb = C + b*128;

    // ================= P0 =================
    if (wv == 0) {
        #pragma unroll
        for (int q = 0; q < 4; ++q)
            ((float4*)sEmb)[lane + 64*q] = ((const float4*)EMB)[lane + 64*q];
        if (lane < 32) ((float4*)sC)[lane] = ((const float4*)Cb)[lane];
        if (lane >= 32 && lane < 41) {            // v1i[f] = W1[f][:] . a1_i
            int f = lane - 32; float a = 0.f;
            for (int q = 0; q < 16; ++q) {
                float4 w = *(const float4*)(W1 + f*64 + q*4);
                float4 x = *(const float4*)(A1 + q*4);
                a += w.x*x.x + w.y*x.y + w.z*x.z + w.w*x.w;
            }
            v1i[f] = a;
        } else if (lane >= 48 && lane < 57) {     // v1j
            int f = lane - 48; float a = 0.f;
            for (int q = 0; q < 16; ++q) {
                float4 w = *(const float4*)(W1 + f*64 + q*4);
                float4 x = *(const float4*)(A1 + 64 + q*4);
                a += w.x*x.x + w.y*x.y + w.z*x.z + w.w*x.w;
            }
            v1j[f] = a;
        }
    } else if (wv == 3) {                         // v2i/v2j[k] = W2[k][:] . a2_{i,j}
        float ai = 0.f, aj = 0.f;
        for (int q = 0; q < 16; ++q) {
            float4 w  = *(const float4*)(W2 + lane*64 + q*4);
            float4 xi = *(const float4*)(A2 + q*4);
            float4 xj = *(const float4*)(A2 + 64 + q*4);
            ai += w.x*xi.x + w.y*xi.y + w.z*xi.z + w.w*xi.w;
            aj += w.x*xj.x + w.y*xj.y + w.z*xj.z + w.w*xj.w;
        }
        v2i[lane] = ai; v2j[lane] = aj;
    } else if (wv == 1) {                         // q_mlp head (wave-private)
        float a = 0.f;
        for (int k = 0; k < 128; k += 4) {
            float4 c4 = *(const float4*)(Cb + k);
            a += c4.x*MLP1W[k*64+lane] + c4.y*MLP1W[(k+1)*64+lane]
               + c4.z*MLP1W[(k+2)*64+lane] + c4.w*MLP1W[(k+3)*64+lane];
        }
        sScr[lane] = fmaxf(a + MLP1B[lane], 0.f);
        float a2 = 0.f;
        for (int k = 0; k < 64; ++k) a2 += sScr[k] * MLP2W[k*64 + lane];
        float x2 = fmaxf(a2 + MLP2B[lane], 0.f);
        float p1 = x2 * HMW[lane];
        #pragma unroll
        for (int off = 32; off >= 1; off >>= 1) p1 += __shfl_down(p1, off);
        if (lane == 0) sScr[128] = p1 + HMB[0];
    } else {                                      // wv==2: gate head (wave-private)
        float a = 0.f;
        for (int k = 0; k < 128; k += 4) {
            float4 c4 = *(const float4*)(Cb + k);
            a += c4.x*G1W[k*64+lane] + c4.y*G1W[(k+1)*64+lane]
               + c4.z*G1W[(k+2)*64+lane] + c4.w*G1W[(k+3)*64+lane];
        }
        float g1 = fmaxf(a + G1B[lane], 0.f);
        float p2 = g1 * G2W[lane];
        #pragma unroll
        for (int off = 32; off >= 1; off >>= 1) p2 += __shfl_down(p2, off);
        if (lane == 0) sScr[129] = 1.f / (1.f + __expf(-(p2 + G2B[0])));
    }
    __syncthreads();   // b1

    // ===== P1: Wh1 = x_g @ W1 via MFMA (K=32, k>=9 zero), write transposed to R1 =====
    {
        v8s Af[2];
        #pragma unroll
        for (int s = 0; s < 2; ++s) {
            const int row = 16*(wv + 4*s) + l15;
            float av[8];
            #pragma unroll
            for (int j = 0; j < 8; ++j) av[j] = 0.f;
            if (q4 == 0) {
                av[0] = sC[row];
                float4 e0 = *(const float4*)(sEmb + row*8);
                float4 e1 = *(const float4*)(sEmb + row*8 + 4);
                av[1]=e0.x; av[2]=e0.y; av[3]=e0.z; av[4]=e0.w;
                av[5]=e1.x; av[6]=e1.y; av[7]=e1.z;
            } else if (q4 == 1) {
                av[0] = sEmb[row*8 + 7];
            }
            Af[s] = pack8(av);
        }
        #pragma unroll
        for (int ct = 0; ct < 4; ++ct) {
            const int col = 16*ct + l15;
            float bv[8];
            #pragma unroll
            for (int j = 0; j < 8; ++j) bv[j] = 0.f;
            if (q4 == 0) {
                #pragma unroll
                for (int j = 0; j < 8; ++j) bv[j] = W1[j*64 + col];
            } else if (q4 == 1) {
                bv[0] = W1[8*64 + col];
            }
            v8s Bf1 = pack8(bv);
            v4f a0 = (v4f){0.f,0.f,0.f,0.f}, a1 = (v4f){0.f,0.f,0.f,0.f};
            a0 = __builtin_amdgcn_mfma_f32_16x16x32_bf16(Af[0], Bf1, a0, 0,0,0);
            a1 = __builtin_amdgcn_mfma_f32_16x16x32_bf16(Af[1], Bf1, a1, 0,0,0);
            uint2 p0, p1;
            p0.x = pk2bf(a0[0], a0[1]); p0.y = pk2bf(a0[2], a0[3]);
            p1.x = pk2bf(a1[0], a1[1]); p1.y = pk2bf(a1[2], a1[3]);
            *(uint2*)(R1 + col*136 + 16*wv      + 4*q4) = p0;
            *(uint2*)(R1 + col*136 + 16*(wv+4)  + 4*q4) = p1;
        }
    }
    {
        // e1: thread t handles row t>>1; even threads -> ei, odd -> ej
        const int row = t >> 1;
        const float* vv = (t & 1) ? v1j : v1i;
        float c = sC[row];
        float4 e0 = *(const float4*)(sEmb + row*8);
        float4 e1 = *(const float4*)(sEmb + row*8 + 4);
        float e = c*vv[0] + e0.x*vv[1]+e0.y*vv[2]+e0.z*vv[3]+e0.w*vv[4]
                          + e1.x*vv[5]+e1.y*vv[6]+e1.z*vv[7]+e1.w*vv[8];
        if (t & 1) { sEj[row] = __expf(e); sFj[row] = __expf(0.2f*e); }
        else       { sEi[row] = __expf(e); sFi[row] = __expf(0.2f*e); }
    }
    __syncthreads();   // b2

    // ================= flash S1@Wh1 =================
    uint2 h1p[2][4];   // packed bf16 residual, C-layout (this thread's values)
    {
        v4f acc[2][4]; float invD[2];
        flash_att(wv, l15, q4, ADJ, sEi, sFi, sEj, sFj, R1, acc, invD);
        __syncthreads();   // b3: all flash1 LDS reads done; R1 + sE/F may be overwritten

        // ===== epi1: 1/D, ELU, LN1 -> H1 into R1; e2-vectors folded in =====
        float g4[4], b4[4], v2i4[4], v2j4[4];
        #pragma unroll
        for (int ct = 0; ct < 4; ++ct) {
            g4[ct] = LN1G[16*ct + l15]; b4[ct] = LN1B[16*ct + l15];
            v2i4[ct] = v2i[16*ct + l15]; v2j4[ct] = v2j[16*ct + l15];
        }
        #pragma unroll
        for (int s = 0; s < 2; ++s) {
            float hprev[4];
            #pragma unroll
            for (int reg = 0; reg < 4; ++reg) {
                const int ro = 16*(wv + 4*s) + 4*q4 + reg;
                const float rd = __shfl(invD[s], 4*q4 + reg);
                float x[4], s1 = 0.f, s2 = 0.f;
                #pragma unroll
                for (int ct = 0; ct < 4; ++ct) {
                    float v = acc[s][ct][reg] * rd;
                    v = (v > 0.f) ? v : (__expf(v) - 1.f);      // ELU
                    x[ct] = v; s1 += v; s2 += v*v;
                }
                s1 += __shfl_xor(s1, 1); s2 += __shfl_xor(s2, 1);
                s1 += __shfl_xor(s1, 2); s2 += __shfl_xor(s2, 2);
                s1 += __shfl_xor(s1, 4); s2 += __shfl_xor(s2, 4);
                s1 += __shfl_xor(s1, 8); s2 += __shfl_xor(s2, 8);
                const float mean = s1 * (1.f/64.f);
                const float var  = s2 * (1.f/64.f) - mean*mean;
                const float rstd = rsqrtf(var + 1e-5f);
                float pi = 0.f, pj = 0.f;
                #pragma unroll
                for (int ct = 0; ct < 4; ++ct) {
                    float h = (x[ct] - mean) * rstd * g4[ct] + b4[ct];
                    R1[ro*72 + 16*ct + l15] = f2bfr(h);          // H1
                    pi += h * v2i4[ct]; pj += h * v2j4[ct];
                    if ((reg & 1) == 0) hprev[ct] = h;
                    else if (reg == 1)  h1p[s][ct].x = pk2bf(hprev[ct], h);
                    else                h1p[s][ct].y = pk2bf(hprev[ct], h);
                }
                pi += __shfl_xor(pi, 1); pj += __shfl_xor(pj, 1);
                pi += __shfl_xor(pi, 2); pj += __shfl_xor(pj, 2);
                pi += __shfl_xor(pi, 4); pj += __shfl_xor(pj, 4);
                pi += __shfl_xor(pi, 8); pj += __shfl_xor(pj, 8);
                if (l15 == 0) {
                    sEi[ro] = __expf(pi); sFi[ro] = __expf(0.2f*pi);
                    sEj[ro] = __expf(pj); sFj[ro] = __expf(0.2f*pj);
                }
            }
        }
    }
    __syncthreads();   // b4: H1 + e2 exps ready

    // ================= P6: Wh2 = h1 @ W2 (A-reads, fence, MFMA, write Wh2T) =================
    {
        v8s Afrag[2][2];
        #pragma unroll
        for (int s = 0; s < 2; ++s)
            #pragma unroll
            for (int ks = 0; ks < 2; ++ks)
                Afrag[s][ks] = *(const v8s*)(R1 + (16*(wv+4*s) + l15)*72 + ks*32 + q4*8);
        __syncthreads();   // b5: all H1 reads done; R1 may be overwritten

        v4f acc2[2][4];
        #pragma unroll
        for (int s = 0; s < 2; ++s)
            #pragma unroll
            for (int ct = 0; ct < 4; ++ct) acc2[s][ct] = (v4f){0.f,0.f,0.f,0.f};
        #pragma unroll
        for (int ks = 0; ks < 2; ++ks) {
            const int kb = ks*32 + q4*8;
            #pragma unroll
            for (int ct = 0; ct < 4; ++ct) {
                const float* wp = W2 + kb*64 + 16*ct + l15;
                float w8[8];
                #pragma unroll
                for (int j = 0; j < 8; ++j) w8[j] = wp[j*64];
                v8s Bf = pack8(w8);
                #pragma unroll
                for (int s = 0; s < 2; ++s)
                    acc2[s][ct] = __builtin_amdgcn_mfma_f32_16x16x32_bf16(Afrag[s][ks], Bf, acc2[s][ct], 0,0,0);
            }
        }
        #pragma unroll
        for (int s = 0; s < 2; ++s) {
            const int rb = 16*(wv+4*s) + 4*q4;
            #pragma unroll
            for (int ct = 0; ct < 4; ++ct) {
                const int col = 16*ct + l15;
                uint2 p;
                p.x = pk2bf(acc2[s][ct][0], acc2[s][ct][1]);
                p.y = pk2bf(acc2[s][ct][2], acc2[s][ct][3]);
                *(uint2*)(R1 + col*136 + rb) = p;                // Wh2T
            }
        }
    }
    __syncthreads();   // b6

    // ================= flash S2@Wh2 + (1/D, +h1 relu, LN2, colsum) =================
    {
        v4f acc[2][4]; float invD[2];
        flash_att(wv, l15, q4, ADJ, sEi, sFi, sEj, sFj, R1, acc, invD);

        float g4[4], b4[4], colsum[4];
        #pragma unroll
        for (int ct = 0; ct < 4; ++ct) {
            g4[ct] = LN2G[16*ct + l15]; b4[ct] = LN2B[16*ct + l15]; colsum[ct] = 0.f;
        }
        #pragma unroll
        for (int s = 0; s < 2; ++s) {
            #pragma unroll
            for (int reg = 0; reg < 4; ++reg) {
                const float rd = __shfl(invD[s], 4*q4 + reg);
                float x[4], s1 = 0.f, s2 = 0.f;
                #pragma unroll
                for (int ct = 0; ct < 4; ++ct) {
                    u32 w = (reg < 2) ? h1p[s][ct].x : h1p[s][ct].y;
                    float h1v = (reg & 1) ? bfhi(w) : bflo(w);
                    float v = fmaxf(acc[s][ct][reg] * rd + h1v, 0.f);
                    x[ct] = v; s1 += v; s2 += v*v;
                }
                s1 += __shfl_xor(s1, 1); s2 += __shfl_xor(s2, 1);
                s1 += __shfl_xor(s1, 2); s2 += __shfl_xor(s2, 2);
                s1 += __shfl_xor(s1, 4); s2 += __shfl_xor(s2, 4);
                s1 += __shfl_xor(s1, 8); s2 += __shfl_xor(s2, 8);
                const float mean = s1 * (1.f/64.f);
                const float var  = s2 * (1.f/64.f) - mean*mean;
                const float rstd = rsqrtf(var + 1e-5f);
                #pragma unroll
                for (int ct = 0; ct < 4; ++ct)
                    colsum[ct] += (x[ct] - mean) * rstd * g4[ct] + b4[ct];
            }
        }
        #pragma unroll
        for (int ct = 0; ct < 4; ++ct) {
            colsum[ct] += __shfl_xor(colsum[ct], 16);
            colsum[ct] += __shfl_xor(colsum[ct], 32);
        }
        if (lane < 16) {
            #pragma unroll
            for (int ct = 0; ct < 4; ++ct) colp[wv*64 + ct*16 + lane] = colsum[ct];
        }
    }
    __syncthreads();   // b7

    // ================= final combine (wave 0) =================
    if (wv == 0) {
        float s = colp[lane] + colp[64 + lane] + colp[128 + lane] + colp[192 + lane];
        float p = s * (1.f/128.f) * HGW[lane];
        #pragma unroll
        for (int off = 32; off >= 1; off >>= 1) p += __shfl_down(p, off);
        if (lane == 0) OUT[b] = sScr[128] + sScr[129] * (p + HGB[0]);
    }
}

extern "C" void kernel_launch(void* const* d_in, const int* in_sizes, int n_in,
                              void* d_out, int out_size, void* d_ws, size_t ws_size,
                              hipStream_t stream) {
    (void)n_in; (void)out_size; (void)d_ws; (void)ws_size;
    const float* C     = (const float*)d_in[0];
    const float* ADJ   = (const float*)d_in[1];
    const float* EMB   = (const float*)d_in[2];
    const float* W1    = (const float*)d_in[3];
    const float* A1    = (const float*)d_in[4];
    const float* W2    = (const float*)d_in[5];
    const float* A2    = (const float*)d_in[6];
    const float* LN1G  = (const float*)d_in[7];
    const float* LN1B  = (const float*)d_in[8];
    const float* LN2G  = (const float*)d_in[9];
    const float* LN2B  = (const float*)d_in[10];
    const float* HGW   = (const float*)d_in[11];
    const float* HGB   = (const float*)d_in[12];
    const float* MLP1W = (const float*)d_in[13];
    const float* MLP1B = (const float*)d_in[14];
    const float* MLP2W = (const float*)d_in[15];
    const float* MLP2B = (const float*)d_in[16];
    const float* HMW   = (const float*)d_in[17];
    const float* HMB   = (const float*)d_in[18];
    const float* G1W   = (const float*)d_in[19];
    const float* G1B   = (const float*)d_in[20];
    const float* G2W   = (const float*)d_in[21];
    const float* G2B   = (const float*)d_in[22];

    const int B = in_sizes[0] / 128;  // 1024

    graphmixer_kernel<<<dim3(B), dim3(256), 0, stream>>>(
        C, ADJ, EMB, W1, A1, W2, A2, LN1G, LN1B, LN2G, LN2B,
        HGW, HGB, MLP1W, MLP1B, MLP2W, MLP2B, HMW, HMB,
        G1W, G1B, G2W, G2B, (float*)d_out);
}

// Round 11
// 133.742 us; speedup vs baseline: 1.0123x; 1.0123x over previous
//
#include <hip/hip_runtime.h>

typedef unsigned short u16;
typedef unsigned int u32;
typedef short v8s __attribute__((ext_vector_type(8)));
typedef float v4f __attribute__((ext_vector_type(4)));
typedef float v2f __attribute__((ext_vector_type(2)));

__device__ __forceinline__ float bflo(u32 d){union{u32 i;float f;}u;u.i=d<<16;return u.f;}
__device__ __forceinline__ float bfhi(u32 d){union{u32 i;float f;}u;u.i=d&0xffff0000u;return u.f;}
__device__ __forceinline__ u16 f2bfr(float f){union{float f;u32 i;}u;u.f=f;return (u16)((u.i+0x8000u)>>16);}
__device__ __forceinline__ u32 pk2bf(float a,float b){
    union{float f;u32 i;}ua,ub; ua.f=a; ub.f=b;
    u32 x = ua.i + 0x8000u, y = ub.i + 0x8000u;
    return __builtin_amdgcn_perm(y, x, 0x07060302);
}
__device__ __forceinline__ v8s pack8(const float* w){
    union { uint4 u; v8s v; } c;
    c.u.x = pk2bf(w[0],w[1]); c.u.y = pk2bf(w[2],w[3]);
    c.u.z = pk2bf(w[4],w[5]); c.u.w = pk2bf(w[6],w[7]);
    return c.v;
}

// Dual-batch flash S@Wh: adj loads shared; A/B chains independent (ILP).
// w = adj * max(Ei*Ej, Fi*Fj) == adj * exp(lrelu(ei+ej))
__device__ __forceinline__ void flash_att2(
    int wv, int l15, int q4, const float* __restrict__ ADJ,
    const float* __restrict__ sEiA, const float* __restrict__ sFiA,
    const float* __restrict__ sEjA, const float* __restrict__ sFjA,
    const float* __restrict__ sEiB, const float* __restrict__ sFiB,
    const float* __restrict__ sEjB, const float* __restrict__ sFjB,
    const u16* __restrict__ R1A, const u16* __restrict__ R1B,
    v4f accA[2][4], v4f accB[2][4], float invDA[2], float invDB[2])
{
    const int r0 = 16*wv + l15, r1 = r0 + 64;
    const v2f EiA0={sEiA[r0],sEiA[r0]}, FiA0={sFiA[r0],sFiA[r0]};
    const v2f EiA1={sEiA[r1],sEiA[r1]}, FiA1={sFiA[r1],sFiA[r1]};
    const v2f EiB0={sEiB[r0],sEiB[r0]}, FiB0={sFiB[r0],sFiB[r0]};
    const v2f EiB1={sEiB[r1],sEiB[r1]}, FiB1={sFiB[r1],sFiB[r1]};
    v2f DA0={0.f,0.f}, DA1={0.f,0.f}, DB0={0.f,0.f}, DB1={0.f,0.f};
    #pragma unroll
    for (int s = 0; s < 2; ++s)
        #pragma unroll
        for (int ct = 0; ct < 4; ++ct) {
            accA[s][ct] = (v4f){0.f,0.f,0.f,0.f};
            accB[s][ct] = (v4f){0.f,0.f,0.f,0.f};
        }

    #pragma unroll
    for (int ks = 0; ks < 4; ++ks) {
        const int ko = ks*32 + q4*8;
        const v2f* EjA = (const v2f*)(sEjA + ko);
        const v2f* FjA = (const v2f*)(sFjA + ko);
        const v2f* EjB = (const v2f*)(sEjB + ko);
        const v2f* FjB = (const v2f*)(sFjB + ko);
        const v2f* A0p = (const v2f*)(ADJ + r0*128 + ko);
        const v2f* A1p = (const v2f*)(ADJ + r1*128 + ko);
        union { u32 u[4]; v8s v; } PA0, PA1, PB0, PB1;
        #pragma unroll
        for (int p = 0; p < 4; ++p) {
            v2f a0 = A0p[p], a1 = A1p[p];          // shared adj
            v2f EA = EjA[p], FA = FjA[p];
            v2f EB = EjB[p], FB = FjB[p];
            v2f xA0 = __builtin_elementwise_max(EiA0*EA, FiA0*FA) * a0;
            v2f xA1 = __builtin_elementwise_max(EiA1*EA, FiA1*FA) * a1;
            v2f xB0 = __builtin_elementwise_max(EiB0*EB, FiB0*FB) * a0;
            v2f xB1 = __builtin_elementwise_max(EiB1*EB, FiB1*FB) * a1;
            DA0 += xA0; DA1 += xA1; DB0 += xB0; DB1 += xB1;
            PA0.u[p] = pk2bf(xA0.x, xA0.y);
            PA1.u[p] = pk2bf(xA1.x, xA1.y);
            PB0.u[p] = pk2bf(xB0.x, xB0.y);
            PB1.u[p] = pk2bf(xB1.x, xB1.y);
        }
        #pragma unroll
        for (int ct = 0; ct < 4; ++ct) {
            v8s BA = *(const v8s*)(R1A + (16*ct + l15)*136 + ko);
            v8s BB = *(const v8s*)(R1B + (16*ct + l15)*136 + ko);
            accA[0][ct] = __builtin_amdgcn_mfma_f32_16x16x32_bf16(PA0.v, BA, accA[0][ct], 0,0,0);
            accA[1][ct] = __builtin_amdgcn_mfma_f32_16x16x32_bf16(PA1.v, BA, accA[1][ct], 0,0,0);
            accB[0][ct] = __builtin_amdgcn_mfma_f32_16x16x32_bf16(PB0.v, BB, accB[0][ct], 0,0,0);
            accB[1][ct] = __builtin_amdgcn_mfma_f32_16x16x32_bf16(PB1.v, BB, accB[1][ct], 0,0,0);
        }
    }
    float dA0 = DA0.x + DA0.y, dA1 = DA1.x + DA1.y;
    float dB0 = DB0.x + DB0.y, dB1 = DB1.x + DB1.y;
    dA0 += __shfl_xor(dA0, 16); dA0 += __shfl_xor(dA0, 32);
    dA1 += __shfl_xor(dA1, 16); dA1 += __shfl_xor(dA1, 32);
    dB0 += __shfl_xor(dB0, 16); dB0 += __shfl_xor(dB0, 32);
    dB1 += __shfl_xor(dB1, 16); dB1 += __shfl_xor(dB1, 32);
    invDA[0] = 1.f / dA0; invDA[1] = 1.f / dA1;
    invDB[0] = 1.f / dB0; invDB[1] = 1.f / dB1;
}

// epi1: 1/D, ELU, LN1 -> H1 into R1 (layout [128][72]); e2-vectors folded; residual kept packed.
__device__ __forceinline__ void epi1(
    int wv, int l15, int q4,
    const v4f acc[2][4], const float invD[2],
    const float* __restrict__ LN1G, const float* __restrict__ LN1B,
    const float* __restrict__ v2i, const float* __restrict__ v2j,
    u16* __restrict__ R1,
    float* __restrict__ sEi, float* __restrict__ sFi,
    float* __restrict__ sEj, float* __restrict__ sFj,
    uint2 h1p[2][4])
{
    float g4[4], b4[4], v2i4[4], v2j4[4];
    #pragma unroll
    for (int ct = 0; ct < 4; ++ct) {
        g4[ct] = LN1G[16*ct + l15]; b4[ct] = LN1B[16*ct + l15];
        v2i4[ct] = v2i[16*ct + l15]; v2j4[ct] = v2j[16*ct + l15];
    }
    #pragma unroll
    for (int s = 0; s < 2; ++s) {
        float hprev[4];
        #pragma unroll
        for (int reg = 0; reg < 4; ++reg) {
            const int ro = 16*(wv + 4*s) + 4*q4 + reg;
            const float rd = __shfl(invD[s], 4*q4 + reg);
            float x[4], s1 = 0.f, s2 = 0.f;
            #pragma unroll
            for (int ct = 0; ct < 4; ++ct) {
                float v = acc[s][ct][reg] * rd;
                v = (v > 0.f) ? v : (__expf(v) - 1.f);      // ELU
                x[ct] = v; s1 += v; s2 += v*v;
            }
            s1 += __shfl_xor(s1, 1); s2 += __shfl_xor(s2, 1);
            s1 += __shfl_xor(s1, 2); s2 += __shfl_xor(s2, 2);
            s1 += __shfl_xor(s1, 4); s2 += __shfl_xor(s2, 4);
            s1 += __shfl_xor(s1, 8); s2 += __shfl_xor(s2, 8);
            const float mean = s1 * (1.f/64.f);
            const float var  = s2 * (1.f/64.f) - mean*mean;
            const float rstd = rsqrtf(var + 1e-5f);
            float pi = 0.f, pj = 0.f;
            #pragma unroll
            for (int ct = 0; ct < 4; ++ct) {
                float h = (x[ct] - mean) * rstd * g4[ct] + b4[ct];
                R1[ro*72 + 16*ct + l15] = f2bfr(h);          // H1
                pi += h * v2i4[ct]; pj += h * v2j4[ct];
                if ((reg & 1) == 0) hprev[ct] = h;
                else if (reg == 1)  h1p[s][ct].x = pk2bf(hprev[ct], h);
                else                h1p[s][ct].y = pk2bf(hprev[ct], h);
            }
            pi += __shfl_xor(pi, 1); pj += __shfl_xor(pj, 1);
            pi += __shfl_xor(pi, 2); pj += __shfl_xor(pj, 2);
            pi += __shfl_xor(pi, 4); pj += __shfl_xor(pj, 4);
            pi += __shfl_xor(pi, 8); pj += __shfl_xor(pj, 8);
            if (l15 == 0) {
                sEi[ro] = __expf(pi); sFi[ro] = __expf(0.2f*pi);
                sEj[ro] = __expf(pj); sFj[ro] = __expf(0.2f*pj);
            }
        }
    }
}

// epi2: 1/D, +h1 relu, LN2, column partial sums -> colp
__device__ __forceinline__ void epi2(
    int lane, int wv, int l15, int q4,
    const v4f acc[2][4], const float invD[2],
    const uint2 h1p[2][4],
    const float* __restrict__ LN2G, const float* __restrict__ LN2B,
    float* __restrict__ colp)
{
    float g4[4], b4[4], colsum[4];
    #pragma unroll
    for (int ct = 0; ct < 4; ++ct) {
        g4[ct] = LN2G[16*ct + l15]; b4[ct] = LN2B[16*ct + l15]; colsum[ct] = 0.f;
    }
    #pragma unroll
    for (int s = 0; s < 2; ++s) {
        #pragma unroll
        for (int reg = 0; reg < 4; ++reg) {
            const float rd = __shfl(invD[s], 4*q4 + reg);
            float x[4], s1 = 0.f, s2 = 0.f;
            #pragma unroll
            for (int ct = 0; ct < 4; ++ct) {
                u32 w = (reg < 2) ? h1p[s][ct].x : h1p[s][ct].y;
                float h1v = (reg & 1) ? bfhi(w) : bflo(w);
                float v = fmaxf(acc[s][ct][reg] * rd + h1v, 0.f);
                x[ct] = v; s1 += v; s2 += v*v;
            }
            s1 += __shfl_xor(s1, 1); s2 += __shfl_xor(s2, 1);
            s1 += __shfl_xor(s1, 2); s2 += __shfl_xor(s2, 2);
            s1 += __shfl_xor(s1, 4); s2 += __shfl_xor(s2, 4);
            s1 += __shfl_xor(s1, 8); s2 += __shfl_xor(s2, 8);
            const float mean = s1 * (1.f/64.f);
            const float var  = s2 * (1.f/64.f) - mean*mean;
            const float rstd = rsqrtf(var + 1e-5f);
            #pragma unroll
            for (int ct = 0; ct < 4; ++ct)
                colsum[ct] += (x[ct] - mean) * rstd * g4[ct] + b4[ct];
        }
    }
    #pragma unroll
    for (int ct = 0; ct < 4; ++ct) {
        colsum[ct] += __shfl_xor(colsum[ct], 16);
        colsum[ct] += __shfl_xor(colsum[ct], 32);
    }
    if (lane < 16) {
        #pragma unroll
        for (int ct = 0; ct < 4; ++ct) colp[wv*64 + ct*16 + lane] = colsum[ct];
    }
}

// Two batches per block. LDS ~46.7 KB -> 2+ blocks/CU; grid 512 = 2 blocks/CU exactly.
// launch_bounds(256,2): VGPR cap 256 -> dual-batch state fits with NO spills.
__global__ __launch_bounds__(256, 2) void graphmixer_kernel(
    const float* __restrict__ C,     // (1024,128)
    const float* __restrict__ ADJ,   // (128,128)
    const float* __restrict__ EMB,   // (128,8)
    const float* __restrict__ W1,    // (9,64)
    const float* __restrict__ A1,    // (128)
    const float* __restrict__ W2,    // (64,64)
    const float* __restrict__ A2,    // (128)
    const float* __restrict__ LN1G, const float* __restrict__ LN1B,
    const float* __restrict__ LN2G, const float* __restrict__ LN2B,
    const float* __restrict__ HGW,  const float* __restrict__ HGB,
    const float* __restrict__ MLP1W, const float* __restrict__ MLP1B,
    const float* __restrict__ MLP2W, const float* __restrict__ MLP2B,
    const float* __restrict__ HMW,  const float* __restrict__ HMB,
    const float* __restrict__ G1W,  const float* __restrict__ G1B,
    const float* __restrict__ G2W,  const float* __restrict__ G2B,
    float* __restrict__ OUT)
{
    const int bx = blockIdx.x, t = threadIdx.x;
    const int lane = t & 63, wv = t >> 6;
    const int l15 = lane & 15, q4 = lane >> 4;
    const int bA = 2*bx, bB = 2*bx + 1;

    __shared__ __align__(16) unsigned char smem[47808];
    u16*   R1A  = (u16*)(smem);            // 18432: Wh1T[64][136] -> H1[128][72] -> Wh2T
    u16*   R1B  = (u16*)(smem + 18432);    // 18432
    float* sEiA = (float*)(smem + 36864);
    float* sFiA = (float*)(smem + 37376);
    float* sEjA = (float*)(smem + 37888);
    float* sFjA = (float*)(smem + 38400);
    float* sEiB = (float*)(smem + 38912);
    float* sFiB = (float*)(smem + 39424);
    float* sEjB = (float*)(smem + 39936);
    float* sFjB = (float*)(smem + 40448);
    float* v2i  = (float*)(smem + 40960);  // 64 (shared weights)
    float* v2j  = (float*)(smem + 41216);  // 64
    float* v1i  = (float*)(smem + 41472);  // 16
    float* v1j  = (float*)(smem + 41536);  // 16
    float* sScrA= (float*)(smem + 41600);  // 136
    float* sScrB= (float*)(smem + 42144);  // 136
    float* sEmb = (float*)(smem + 42688);  // 1024 f32 (live P0..b2)
    float* sCA  = (float*)(smem + 46784);  // 128
    float* sCB  = (float*)(smem + 47296);  // 128
    float* colpA= (float*)(smem + 42688);  // 256 (alias sEmb; live after b6)
    float* colpB= (float*)(smem + 43712);  // 256

    const float* CbA = C + bA*128;
    const float* CbB = C + bB*128;

    // ================= P0 =================
    if (wv == 0) {
        #pragma unroll
        for (int q = 0; q < 4; ++q)
            ((float4*)sEmb)[lane + 64*q] = ((const float4*)EMB)[lane + 64*q];
        if (lane < 32) ((float4*)sCA)[lane] = ((const float4*)CbA)[lane];
        else           ((float4*)sCB)[lane - 32] = ((const float4*)CbB)[lane - 32];
        if (lane >= 32 && lane < 41) {            // v1i[f] = W1[f][:] . a1_i
            int f = lane - 32; float a = 0.f;
            for (int q = 0; q < 16; ++q) {
                float4 w = *(const float4*)(W1 + f*64 + q*4);
                float4 x = *(const float4*)(A1 + q*4);
                a += w.x*x.x + w.y*x.y + w.z*x.z + w.w*x.w;
            }
            v1i[f] = a;
        } else if (lane >= 48 && lane < 57) {     // v1j
            int f = lane - 48; float a = 0.f;
            for (int q = 0; q < 16; ++q) {
                float4 w = *(const float4*)(W1 + f*64 + q*4);
                float4 x = *(const float4*)(A1 + 64 + q*4);
                a += w.x*x.x + w.y*x.y + w.z*x.z + w.w*x.w;
            }
            v1j[f] = a;
        }
        // gate head, batch B
        float a = 0.f;
        for (int k = 0; k < 128; k += 4) {
            float4 c4 = *(const float4*)(CbB + k);
            a += c4.x*G1W[k*64+lane] + c4.y*G1W[(k+1)*64+lane]
               + c4.z*G1W[(k+2)*64+lane] + c4.w*G1W[(k+3)*64+lane];
        }
        float g1 = fmaxf(a + G1B[lane], 0.f);
        float p2 = g1 * G2W[lane];
        #pragma unroll
        for (int off = 32; off >= 1; off >>= 1) p2 += __shfl_down(p2, off);
        if (lane == 0) sScrB[129] = 1.f / (1.f + __expf(-(p2 + G2B[0])));
    } else if (wv == 1) {                         // q_mlp head, batch A
        float a = 0.f;
        for (int k = 0; k < 128; k += 4) {
            float4 c4 = *(const float4*)(CbA + k);
            a += c4.x*MLP1W[k*64+lane] + c4.y*MLP1W[(k+1)*64+lane]
               + c4.z*MLP1W[(k+2)*64+lane] + c4.w*MLP1W[(k+3)*64+lane];
        }
        sScrA[lane] = fmaxf(a + MLP1B[lane], 0.f);
        float a2 = 0.f;
        for (int k = 0; k < 64; ++k) a2 += sScrA[k] * MLP2W[k*64 + lane];
        float x2 = fmaxf(a2 + MLP2B[lane], 0.f);
        float p1 = x2 * HMW[lane];
        #pragma unroll
        for (int off = 32; off >= 1; off >>= 1) p1 += __shfl_down(p1, off);
        if (lane == 0) sScrA[128] = p1 + HMB[0];
    } else if (wv == 2) {                         // q_mlp head, batch B
        float a = 0.f;
        for (int k = 0; k < 128; k += 4) {
            float4 c4 = *(const float4*)(CbB + k);
            a += c4.x*MLP1W[k*64+lane] + c4.y*MLP1W[(k+1)*64+lane]
               + c4.z*MLP1W[(k+2)*64+lane] + c4.w*MLP1W[(k+3)*64+lane];
        }
        sScrB[lane] = fmaxf(a + MLP1B[lane], 0.f);
        float a2 = 0.f;
        for (int k = 0; k < 64; ++k) a2 += sScrB[k] * MLP2W[k*64 + lane];
        float x2 = fmaxf(a2 + MLP2B[lane], 0.f);
        float p1 = x2 * HMW[lane];
        #pragma unroll
        for (int off = 32; off >= 1; off >>= 1) p1 += __shfl_down(p1, off);
        if (lane == 0) sScrB[128] = p1 + HMB[0];
    } else {                                      // wv==3: v2 vectors + gate A
        float ai = 0.f, aj = 0.f;
        for (int q = 0; q < 16; ++q) {
            float4 w  = *(const float4*)(W2 + lane*64 + q*4);
            float4 xi = *(const float4*)(A2 + q*4);
            float4 xj = *(const float4*)(A2 + 64 + q*4);
            ai += w.x*xi.x + w.y*xi.y + w.z*xi.z + w.w*xi.w;
            aj += w.x*xj.x + w.y*xj.y + w.z*xj.z + w.w*xj.w;
        }
        v2i[lane] = ai; v2j[lane] = aj;
        float a = 0.f;
        for (int k = 0; k < 128; k += 4) {
            float4 c4 = *(const float4*)(CbA + k);
            a += c4.x*G1W[k*64+lane] + c4.y*G1W[(k+1)*64+lane]
               + c4.z*G1W[(k+2)*64+lane] + c4.w*G1W[(k+3)*64+lane];
        }
        float g1 = fmaxf(a + G1B[lane], 0.f);
        float p2 = g1 * G2W[lane];
        #pragma unroll
        for (int off = 32; off >= 1; off >>= 1) p2 += __shfl_down(p2, off);
        if (lane == 0) sScrA[129] = 1.f / (1.f + __expf(-(p2 + G2B[0])));
    }
    __syncthreads();   // b1

    // ===== P1: Wh1 = x_g @ W1 via MFMA for both batches (shared B-fragments) =====
    {
        v8s AfA[2], AfB[2];
        #pragma unroll
        for (int s = 0; s < 2; ++s) {
            const int row = 16*(wv + 4*s) + l15;
            float avA[8], avB[8];
            #pragma unroll
            for (int j = 0; j < 8; ++j) { avA[j] = 0.f; avB[j] = 0.f; }
            if (q4 == 0) {
                float4 e0 = *(const float4*)(sEmb + row*8);
                float4 e1 = *(const float4*)(sEmb + row*8 + 4);
                avA[0] = sCA[row];
                avA[1]=e0.x; avA[2]=e0.y; avA[3]=e0.z; avA[4]=e0.w;
                avA[5]=e1.x; avA[6]=e1.y; avA[7]=e1.z;
                avB[0] = sCB[row];
                avB[1]=e0.x; avB[2]=e0.y; avB[3]=e0.z; avB[4]=e0.w;
                avB[5]=e1.x; avB[6]=e1.y; avB[7]=e1.z;
            } else if (q4 == 1) {
                avA[0] = sEmb[row*8 + 7];
                avB[0] = sEmb[row*8 + 7];
            }
            AfA[s] = pack8(avA); AfB[s] = pack8(avB);
        }
        #pragma unroll
        for (int ct = 0; ct < 4; ++ct) {
            const int col = 16*ct + l15;
            float bv[8];
            #pragma unroll
            for (int j = 0; j < 8; ++j) bv[j] = 0.f;
            if (q4 == 0) {
                #pragma unroll
                for (int j = 0; j < 8; ++j) bv[j] = W1[j*64 + col];
            } else if (q4 == 1) {
                bv[0] = W1[8*64 + col];
            }
            v8s Bf1 = pack8(bv);
            v4f aA0 = (v4f){0.f,0.f,0.f,0.f}, aA1 = (v4f){0.f,0.f,0.f,0.f};
            v4f aB0 = (v4f){0.f,0.f,0.f,0.f}, aB1 = (v4f){0.f,0.f,0.f,0.f};
            aA0 = __builtin_amdgcn_mfma_f32_16x16x32_bf16(AfA[0], Bf1, aA0, 0,0,0);
            aA1 = __builtin_amdgcn_mfma_f32_16x16x32_bf16(AfA[1], Bf1, aA1, 0,0,0);
            aB0 = __builtin_amdgcn_mfma_f32_16x16x32_bf16(AfB[0], Bf1, aB0, 0,0,0);
            aB1 = __builtin_amdgcn_mfma_f32_16x16x32_bf16(AfB[1], Bf1, aB1, 0,0,0);
            uint2 p;
            p.x = pk2bf(aA0[0], aA0[1]); p.y = pk2bf(aA0[2], aA0[3]);
            *(uint2*)(R1A + col*136 + 16*wv     + 4*q4) = p;
            p.x = pk2bf(aA1[0], aA1[1]); p.y = pk2bf(aA1[2], aA1[3]);
            *(uint2*)(R1A + col*136 + 16*(wv+4) + 4*q4) = p;
            p.x = pk2bf(aB0[0], aB0[1]); p.y = pk2bf(aB0[2], aB0[3]);
            *(uint2*)(R1B + col*136 + 16*wv     + 4*q4) = p;
            p.x = pk2bf(aB1[0], aB1[1]); p.y = pk2bf(aB1[2], aB1[3]);
            *(uint2*)(R1B + col*136 + 16*(wv+4) + 4*q4) = p;
        }
    }
    {
        // e1 for both batches: thread t -> row t>>1; even lanes ei, odd ej
        const int row = t >> 1;
        const float* vv = (t & 1) ? v1j : v1i;
        float4 e0 = *(const float4*)(sEmb + row*8);
        float4 e1 = *(const float4*)(sEmb + row*8 + 4);
        float base = e0.x*vv[1]+e0.y*vv[2]+e0.z*vv[3]+e0.w*vv[4]
                   + e1.x*vv[5]+e1.y*vv[6]+e1.z*vv[7]+e1.w*vv[8];
        float eA = sCA[row]*vv[0] + base;
        float eB = sCB[row]*vv[0] + base;
        if (t & 1) {
            sEjA[row] = __expf(eA); sFjA[row] = __expf(0.2f*eA);
            sEjB[row] = __expf(eB); sFjB[row] = __expf(0.2f*eB);
        } else {
            sEiA[row] = __expf(eA); sFiA[row] = __expf(0.2f*eA);
            sEiB[row] = __expf(eB); sFiB[row] = __expf(0.2f*eB);
        }
    }
    __syncthreads();   // b2

    // ================= flash1 (both batches) =================
    uint2 h1pA[2][4], h1pB[2][4];
    {
        v4f accA[2][4], accB[2][4]; float invDA[2], invDB[2];
        flash_att2(wv, l15, q4, ADJ,
                   sEiA, sFiA, sEjA, sFjA, sEiB, sFiB, sEjB, sFjB,
                   R1A, R1B, accA, accB, invDA, invDB);
        __syncthreads();   // b3: flash1 LDS reads done; R1/E/F may be overwritten

        epi1(wv, l15, q4, accA, invDA, LN1G, LN1B, v2i, v2j,
             R1A, sEiA, sFiA, sEjA, sFjA, h1pA);
        epi1(wv, l15, q4, accB, invDB, LN1G, LN1B, v2i, v2j,
             R1B, sEiB, sFiB, sEjB, sFjB, h1pB);
    }
    __syncthreads();   // b4: H1 + e2 exps ready

    // ================= P6: Wh2 = h1 @ W2 (both batches, shared B-frags) =================
    {
        v8s AfrA[2][2], AfrB[2][2];
        #pragma unroll
        for (int s = 0; s < 2; ++s)
            #pragma unroll
            for (int ks = 0; ks < 2; ++ks) {
                AfrA[s][ks] = *(const v8s*)(R1A + (16*(wv+4*s) + l15)*72 + ks*32 + q4*8);
                AfrB[s][ks] = *(const v8s*)(R1B + (16*(wv+4*s) + l15)*72 + ks*32 + q4*8);
            }
        __syncthreads();   // b5: H1 reads done; R1 may be overwritten

        v4f acA[2][4], acB[2][4];
        #pragma unroll
        for (int s = 0; s < 2; ++s)
            #pragma unroll
            for (int ct = 0; ct < 4; ++ct) {
                acA[s][ct] = (v4f){0.f,0.f,0.f,0.f};
                acB[s][ct] = (v4f){0.f,0.f,0.f,0.f};
            }
        #pragma unroll
        for (int ks = 0; ks < 2; ++ks) {
            const int kb = ks*32 + q4*8;
            #pragma unroll
            for (int ct = 0; ct < 4; ++ct) {
                const float* wp = W2 + kb*64 + 16*ct + l15;
                float w8[8];
                #pragma unroll
                for (int j = 0; j < 8; ++j) w8[j] = wp[j*64];
                v8s Bf = pack8(w8);
                #pragma unroll
                for (int s = 0; s < 2; ++s) {
                    acA[s][ct] = __builtin_amdgcn_mfma_f32_16x16x32_bf16(AfrA[s][ks], Bf, acA[s][ct], 0,0,0);
                    acB[s][ct] = __builtin_amdgcn_mfma_f32_16x16x32_bf16(AfrB[s][ks], Bf, acB[s][ct], 0,0,0);
                }
            }
        }
        #pragma unroll
        for (int s = 0; s < 2; ++s) {
            const int rb = 16*(wv+4*s) + 4*q4;
            #pragma unroll
            for (int ct = 0; ct < 4; ++ct) {
                const int col = 16*ct + l15;
                uint2 p;
                p.x = pk2bf(acA[s][ct][0], acA[s][ct][1]);
                p.y = pk2bf(acA[s][ct][2], acA[s][ct][3]);
                *(uint2*)(R1A + col*136 + rb) = p;
                p.x = pk2bf(acB[s][ct][0], acB[s][ct][1]);
                p.y = pk2bf(acB[s][ct][2], acB[s][ct][3]);
                *(uint2*)(R1B + col*136 + rb) = p;
            }
        }
    }
    __syncthreads();   // b6

    // ================= flash2 (both batches) + epilogues =================
    {
        v4f accA[2][4], accB[2][4]; float invDA[2], invDB[2];
        flash_att2(wv, l15, q4, ADJ,
                   sEiA, sFiA, sEjA, sFjA, sEiB, sFiB, sEjB, sFjB,
                   R1A, R1B, accA, accB, invDA, invDB);
        epi2(lane, wv, l15, q4, accA, invDA, h1pA, LN2G, LN2B, colpA);
        epi2(lane, wv, l15, q4, accB, invDB, h1pB, LN2G, LN2B, colpB);
    }
    __syncthreads();   // b7

    // ================= final combine =================
    if (wv == 0) {
        float s = colpA[lane] + colpA[64 + lane] + colpA[128 + lane] + colpA[192 + lane];
        float p = s * (1.f/128.f) * HGW[lane];
        #pragma unroll
        for (int off = 32; off >= 1; off >>= 1) p += __shfl_down(p, off);
        if (lane == 0) OUT[bA] = sScrA[128] + sScrA[129] * (p + HGB[0]);
    } else if (wv == 1) {
        float s = colpB[lane] + colpB[64 + lane] + colpB[128 + lane] + colpB[192 + lane];
        float p = s * (1.f/128.f) * HGW[lane];
        #pragma unroll
        for (int off = 32; off >= 1; off >>= 1) p += __shfl_down(p, off);
        if (lane == 0) OUT[bB] = sScrB[128] + sScrB[129] * (p + HGB[0]);
    }
}

extern "C" void kernel_launch(void* const* d_in, const int* in_sizes, int n_in,
                              void* d_out, int out_size, void* d_ws, size_t ws_size,
                              hipStream_t stream) {
    (void)n_in; (void)out_size; (void)d_ws; (void)ws_size;
    const float* C     = (const float*)d_in[0];
    const float* ADJ   = (const float*)d_in[1];
    const float* EMB   = (const float*)d_in[2];
    const float* W1    = (const float*)d_in[3];
    const float* A1    = (const float*)d_in[4];
    const float* W2    = (const float*)d_in[5];
    const float* A2    = (const float*)d_in[6];
    const float* LN1G  = (const float*)d_in[7];
    const float* LN1B  = (const float*)d_in[8];
    const float* LN2G  = (const float*)d_in[9];
    const float* LN2B  = (const float*)d_in[10];
    const float* HGW   = (const float*)d_in[11];
    const float* HGB   = (const float*)d_in[12];
    const float* MLP1W = (const float*)d_in[13];
    const float* MLP1B = (const float*)d_in[14];
    const float* MLP2W = (const float*)d_in[15];
    const float* MLP2B = (const float*)d_in[16];
    const float* HMW   = (const float*)d_in[17];
    const float* HMB   = (const float*)d_in[18];
    const float* G1W   = (const float*)d_in[19];
    const float* G1B   = (const float*)d_in[20];
    const float* G2W   = (const float*)d_in[21];
    const float* G2B   = (const float*)d_in[22];

    const int B = in_sizes[0] / 128;  // 1024

    graphmixer_kernel<<<dim3(B/2), dim3(256), 0, stream>>>(
        C, ADJ, EMB, W1, A1, W2, A2, LN1G, LN1B, LN2G, LN2B,
        HGW, HGB, MLP1W, MLP1B, MLP2W, MLP2B, HMW, HMB,
        G1W, G1B, G2W, G2B, (float*)d_out);
}